// Round 1
// baseline (15906.073 us; speedup 1.0000x reference)
//
#include <hip/hip_runtime.h>
#include <hip/hip_bf16.h>

typedef __hip_bfloat16 bf16;
typedef __attribute__((ext_vector_type(8))) unsigned short us8;

// Problem constants
constexpr int N_ = 50000;
constexpr int E_ = 800000;
constexpr int C_ = 32;
constexpr int Z_ = 10;

// fp32 weight arena offsets (floats)
constexpr int OFF_EMB  = 0;                    // [Z][C]          320
constexpr int OFF_UPS  = 320;                  // [L][C][C]       2048
constexpr int OFF_UPV  = OFF_UPS + 2048;       // [L][C][C]       2048
constexpr int OFF_R1T  = OFF_UPV + 2048;       // [L][64][8]  (transposed)  1024
constexpr int OFF_R2   = OFF_R1T + 1024;       // [L][64][64]     8192
constexpr int OFF_R3T  = OFF_R2 + 8192;        // [L][32][5][64] (c-major) 20480
constexpr int OFF_OUTS = OFF_R3T + 20480;      // [L][C][C]       2048
constexpr int OFF_OUTV = OFF_OUTS + 2048;      // [L][C][C]       2048
constexpr int OFF_SCS  = OFF_OUTV + 2048;      // [L][Z][C][C]    20480
constexpr int OFF_SCV  = OFF_SCS + 20480;      // [L][Z][C][C]    20480
constexpr int OFF_WP   = OFF_SCV + 20480;      // [L][Z][5][C]    3200
constexpr int OFF_LINS = OFF_WP + 3200;        // [L][C][C]       2048
constexpr int OFF_LINV = OFF_LINS + 2048;      // [L][C][C]       2048
constexpr int W_TOTAL  = OFF_LINV + 2048;      // 86464

// workspace layout, in 4-byte words. Total 14,786,688 words = 56.41 MiB
// (r5-r7 proved 56.03; +0.38 MiB for rowptr + degree-sorted node order)
constexpr size_t O_CNT  = 0;                   // int (unused, kept)
constexpr size_t O_FLAG = 1;                   // int: 1 => float inputs are bf16
constexpr size_t O_DH   = 8;                   // 48 ints: degree histogram/base (inside zeroed 64)
constexpr size_t O_SPEC = 64;                  // N ints (padded 50048)
constexpr size_t O_EIDS = 50112;               // E ints: CSR-ordered active edge ids
constexpr size_t O_POSF = 850112;              // N*3 fp32 (padded 150016)
constexpr size_t O_W    = 1000128;             // W_TOTAL fp32
constexpr size_t O_S    = 1086592;             // N*C fp32 (state s)
constexpr size_t O_VB   = 2686592;             // N*C*3 bf16 (state v, 2400000 words)
constexpr size_t O_SUB  = 5086592;             // N*C bf16   (800000 words)
constexpr size_t O_VUB  = 5886592;             // N*C*3 bf16 (2400000 words)
constexpr size_t O_SS   = 8286592;             // N*C fp32   (S accum)
constexpr size_t O_VV   = 9886592;             // N*C*3 fp32 (V accum) -> ends 14686592
constexpr size_t O_ROWP = 14686592;            // N ints (padded 50048): rowptr (destructive-scan)
constexpr size_t O_NORD = 14736640;            // N ints (padded 50048): degree-sorted node order

struct ConvArgs { const void* p[13]; };

// dual-dtype input load: isb is wave-uniform => scalar branch
__device__ __forceinline__ float ldi(const void* p, int i, int isb) {
    if (isb) return (float)((const bf16*)p)[i];
    return ((const float*)p)[i];
}
__device__ __forceinline__ float b2f(unsigned short u) {   // bf16 bits -> float
    union { unsigned x; float f; } v; v.x = ((unsigned)u) << 16; return v.f;
}
// element i (0..23) of a 24-ushort row held as three us8 (i must fold to constant)
__device__ __forceinline__ float vr24(const us8 a, const us8 b, const us8 c, int i) {
    unsigned short u = (i < 8) ? a[i & 7] : (i < 16) ? b[i & 7] : c[i & 7];
    return b2f(u);
}

// ---- dtype detection on node_attrs (one-hot): word 0x00003F80 occurs only if bf16 ----
__global__ __launch_bounds__(256) void detect_kernel(const unsigned* __restrict__ a,
                                                     int* __restrict__ flag) {
    int t = threadIdx.x;
    int hit = 0;
    for (int i = t; i < 4096; i += 256) hit |= (a[i] == 0x00003F80u) ? 1 : 0;
    if (hit) atomicOr(flag, 1);
}

// ---- weight conversion (-> fp32, with R1/R3 transposes) ----
__global__ __launch_bounds__(256) void convert_kernel(ConvArgs a, const int* __restrict__ flag,
                                                      float* __restrict__ Wc) {
    int t = blockIdx.x * 256 + threadIdx.x;
    if (t >= W_TOTAL) return;
    int isb = *flag;
    int u = t;
    if (u < 320)  { Wc[OFF_EMB + u] = ldi(a.p[0], u, isb); return; }  u -= 320;
    if (u < 2048) { Wc[OFF_UPS + u] = ldi(a.p[1], u, isb); return; }  u -= 2048;
    if (u < 2048) { Wc[OFF_UPV + u] = ldi(a.p[2], u, isb); return; }  u -= 2048;
    if (u < 1024) {                       // R1 [L][8][64] -> R1T [L][64][8]
        int l = u >> 9, r = u & 511, j = r >> 3, k = r & 7;
        Wc[OFF_R1T + u] = ldi(a.p[3], l * 512 + k * 64 + j, isb); return;
    }  u -= 1024;
    if (u < 8192) { Wc[OFF_R2 + u] = ldi(a.p[4], u, isb); return; }   u -= 8192;
    if (u < 20480) {                      // R3 [L][64][160] -> R3T [L][32][5][64] (c-major)
        int l = u / 10240, r = u % 10240, c = r / 320, r2 = r % 320, p = r2 / 64, j = r2 % 64;
        Wc[OFF_R3T + u] = ldi(a.p[5], l * 10240 + j * 160 + p * 32 + c, isb); return;
    }  u -= 20480;
    if (u < 2048)  { Wc[OFF_OUTS + u] = ldi(a.p[6], u, isb);  return; } u -= 2048;
    if (u < 2048)  { Wc[OFF_OUTV + u] = ldi(a.p[7], u, isb);  return; } u -= 2048;
    if (u < 20480) { Wc[OFF_SCS  + u] = ldi(a.p[8], u, isb);  return; } u -= 20480;
    if (u < 20480) { Wc[OFF_SCV  + u] = ldi(a.p[9], u, isb);  return; } u -= 20480;
    if (u < 3200)  { Wc[OFF_WP   + u] = ldi(a.p[10], u, isb); return; } u -= 3200;
    if (u < 2048)  { Wc[OFF_LINS + u] = ldi(a.p[11], u, isb); return; } u -= 2048;
    Wc[OFF_LINV + u] = ldi(a.p[12], u, isb);
}

// ---- positions -> fp32 ----
__global__ __launch_bounds__(256) void posconv_kernel(const void* __restrict__ pos,
                                                      const int* __restrict__ flag,
                                                      float* __restrict__ posf) {
    int t = blockIdx.x * 256 + threadIdx.x;
    if (t >= N_ * 3) return;
    posf[t] = ldi(pos, t, *flag);
}

// ---- species from one-hot ----
__global__ __launch_bounds__(256) void spec_kernel(const void* __restrict__ attrs,
                                                   const int* __restrict__ flag,
                                                   int* __restrict__ spec) {
    int n = blockIdx.x * 256 + threadIdx.x;
    if (n >= N_) return;
    int isb = *flag;
    int z = 0;
    #pragma unroll
    for (int zz = 0; zz < Z_; zz++)
        if (ldi(attrs, n * Z_ + zz, isb) > 0.5f) z = zz;
    spec[n] = z;
}

// ---- s init: s[n][c] = W_embed[spec[n]][c] ----
__global__ __launch_bounds__(256) void sinit_kernel(const float* __restrict__ Wc,
                                                    const int* __restrict__ spec,
                                                    float* __restrict__ s) {
    int t = blockIdx.x * 256 + threadIdx.x;   // N*C threads
    int n = t >> 5, c = t & 31;
    s[t] = Wc[OFF_EMB + spec[n] * C_ + c];
}

// ---- CSR build step 1: per-dst degree of ACTIVE edges (r < RCUT) ----
__global__ __launch_bounds__(256) void deg_kernel(const int* __restrict__ ei,
                                                  const float* __restrict__ posf,
                                                  const void* __restrict__ shifts,
                                                  const int* __restrict__ flag,
                                                  int* __restrict__ rp) {
    int e = blockIdx.x * 256 + threadIdx.x;
    int isb = *flag;
    int s = ei[e], d = ei[E_ + e];
    if (s < 0 || s >= N_ || d < 0 || d >= N_) return;
    float vx = posf[d * 3 + 0] - posf[s * 3 + 0] + ldi(shifts, e * 3 + 0, isb);
    float vy = posf[d * 3 + 1] - posf[s * 3 + 1] + ldi(shifts, e * 3 + 1, isb);
    float vz = posf[d * 3 + 2] - posf[s * 3 + 2] + ldi(shifts, e * 3 + 2, isb);
    if (vx * vx + vy * vy + vz * vz < 25.0f) atomicAdd(rp + d, 1);
}

// ---- CSR build step 2: in-place exclusive prefix sum over rp[0..N) ----
__global__ __launch_bounds__(1024) void scan_kernel(int* __restrict__ rp) {
    __shared__ int ps[1024];
    int t = threadIdx.x;
    constexpr int CH = (N_ + 1023) / 1024;   // 49
    int base = t * CH;
    int sum = 0;
    for (int i = 0; i < CH; i++) {
        int idx = base + i;
        if (idx < N_) sum += rp[idx];
    }
    ps[t] = sum;
    __syncthreads();
    for (int off = 1; off < 1024; off <<= 1) {
        int v = (t >= off) ? ps[t - off] : 0;
        __syncthreads();
        ps[t] += v;
        __syncthreads();
    }
    int run = (t == 0) ? 0 : ps[t - 1];
    for (int i = 0; i < CH; i++) {
        int idx = base + i;
        if (idx < N_) { int v = rp[idx]; rp[idx] = run; run += v; }
    }
}

// ---- CSR build step 3: scatter edge ids (destructive: rp becomes INCLUSIVE prefix) ----
__global__ __launch_bounds__(256) void scatter_kernel(const int* __restrict__ ei,
                                                      const float* __restrict__ posf,
                                                      const void* __restrict__ shifts,
                                                      const int* __restrict__ flag,
                                                      int* __restrict__ rp,
                                                      int* __restrict__ csr) {
    int e = blockIdx.x * 256 + threadIdx.x;
    int isb = *flag;
    int s = ei[e], d = ei[E_ + e];
    if (s < 0 || s >= N_ || d < 0 || d >= N_) return;
    float vx = posf[d * 3 + 0] - posf[s * 3 + 0] + ldi(shifts, e * 3 + 0, isb);
    float vy = posf[d * 3 + 1] - posf[s * 3 + 1] + ldi(shifts, e * 3 + 1, isb);
    float vz = posf[d * 3 + 2] - posf[s * 3 + 2] + ldi(shifts, e * 3 + 2, isb);
    if (vx * vx + vy * vy + vz * vz < 25.0f) {
        int pos = atomicAdd(rp + d, 1);
        csr[pos] = e;
    }
}

// ---- node degree-sort (counting sort, 48 bins, heavy-first) for wave load balance ----
__global__ __launch_bounds__(256) void nhist_kernel(const int* __restrict__ rp,
                                                    int* __restrict__ dh) {
    int n = blockIdx.x * 256 + threadIdx.x;
    if (n >= N_) return;
    int deg = rp[n] - (n ? rp[n - 1] : 0);
    atomicAdd(dh + (47 - min(deg, 47)), 1);
}
__global__ void nscan_kernel(int* __restrict__ dh) {
    if (threadIdx.x == 0) {
        int run = 0;
        for (int i = 0; i < 48; i++) { int v = dh[i]; dh[i] = run; run += v; }
    }
}
__global__ __launch_bounds__(256) void nscatter_kernel(const int* __restrict__ rp,
                                                       int* __restrict__ dh,
                                                       int* __restrict__ nord) {
    int n = blockIdx.x * 256 + threadIdx.x;
    if (n >= N_) return;
    int deg = rp[n] - (n ? rp[n - 1] : 0);
    int pos = atomicAdd(dh + (47 - min(deg, 47)), 1);
    nord[pos] = n;
}

// ---- per-node "up" linear: su = s@Wus, vu = v@Wuv (fp32 math, bf16 outs) ----
__global__ __launch_bounds__(256) void up_kernel(const float* __restrict__ Wc,
                                                 const float* __restrict__ s,
                                                 const bf16* __restrict__ vb,
                                                 bf16* __restrict__ su,
                                                 bf16* __restrict__ vu, int layer) {
    __shared__ float s_sh[8][32];
    __shared__ float v_sh[8][96];
    int tid = threadIdx.x;
    int nl = tid >> 5, d = tid & 31;
    int n = blockIdx.x * 8 + nl;
    s_sh[nl][d]      = s[n * 32 + d];
    v_sh[nl][d]      = (float)vb[n * 96 + d];
    v_sh[nl][d + 32] = (float)vb[n * 96 + d + 32];
    v_sh[nl][d + 64] = (float)vb[n * 96 + d + 64];
    __syncthreads();
    const float* wus = Wc + OFF_UPS + layer * 1024;
    const float* wuv = Wc + OFF_UPV + layer * 1024;
    float a0 = 0.f, b0 = 0.f, b1 = 0.f, b2 = 0.f;
    #pragma unroll 8
    for (int c = 0; c < 32; c++) {
        float wS = wus[c * 32 + d], wV = wuv[c * 32 + d];
        a0 += s_sh[nl][c] * wS;
        b0 += v_sh[nl][c * 3 + 0] * wV;
        b1 += v_sh[nl][c * 3 + 1] * wV;
        b2 += v_sh[nl][c * 3 + 2] * wV;
    }
    su[n * 32 + d] = __float2bfloat16(a0);
    vu[n * 96 + d * 3 + 0] = __float2bfloat16(b0);
    vu[n * 96 + d * 3 + 1] = __float2bfloat16(b1);
    vu[n * 96 + d * 3 + 2] = __float2bfloat16(b2);
}

__device__ __forceinline__ float silu_f(float a) {
    return a / (1.f + __expf(-a));
}

// ---- fused edge kernel, DST-PARALLEL over CSR: one 4-lane group per node ----
// Lane l owns CONTIGUOUS channels c = 8l..8l+7 (vectorized dwordx4 row gathers:
// 4 loads/edge/lane vs 32 scalar gathers before). Messages accumulate in 32
// registers per lane across the node's edge list; S/V written ONCE per node —
// zero atomics (was 128 scattered atomicAdd per edge = 444 MB WRITE_SIZE).
// Nodes are degree-sorted (nord) so the 16 groups per wave have equal loop counts.
__global__ __launch_bounds__(256, 4) void msg_kernel(const int* __restrict__ nord,
                                                     const int* __restrict__ rowp,
                                                     const int* __restrict__ csr,
                                                     const int* __restrict__ ei,
                                                     const float* __restrict__ posf,
                                                     const void* __restrict__ shifts,
                                                     const int* __restrict__ flag,
                                                     const float* __restrict__ Wc,
                                                     const bf16* __restrict__ sub,
                                                     const bf16* __restrict__ vub,
                                                     float* __restrict__ S,
                                                     float* __restrict__ V, int layer) {
    int tid = threadIdx.x;
    int lane = tid & 63;
    int g = lane >> 2, l = lane & 3;
    int gi = blockIdx.x * 64 + (tid >> 6) * 16 + g;
    if (gi >= N_) return;
    int n = nord[gi];
    int beg = (n == 0) ? 0 : rowp[n - 1];   // rowp is inclusive prefix post-scatter
    int end = rowp[n];
    int isb = *flag;
    float dpx = posf[n * 3 + 0], dpy = posf[n * 3 + 1], dpz = posf[n * 3 + 2];
    const int jbase = l * 16;
    const float* r1  = Wc + OFF_R1T + layer * 512;   // [64][8]
    const float* r2w = Wc + OFF_R2  + layer * 4096;  // [64][64]
    const float* r3l = Wc + OFF_R3T + layer * 10240; // [32][5][64] c-major

    float accS[8], accV[24];
    #pragma unroll
    for (int i = 0; i < 8; i++) accS[i] = 0.f;
    #pragma unroll
    for (int i = 0; i < 24; i++) accV[i] = 0.f;

    for (int idx = beg; idx < end; idx++) {
        int e = csr[idx];
        int srcn = ei[e];
        // coalesced row gathers: group of 4 lanes reads the full src row
        us8 sraw = *(const us8*)((const unsigned short*)sub + (size_t)srcn * 32 + 8 * l);
        const unsigned short* vrow = (const unsigned short*)vub + (size_t)srcn * 96 + 24 * l;
        us8 vraw0 = *(const us8*)(vrow);
        us8 vraw1 = *(const us8*)(vrow + 8);
        us8 vraw2 = *(const us8*)(vrow + 16);

        float vx = dpx - posf[srcn * 3 + 0] + ldi(shifts, e * 3 + 0, isb);
        float vy = dpy - posf[srcn * 3 + 1] + ldi(shifts, e * 3 + 1, isb);
        float vz = dpz - posf[srcn * 3 + 2] + ldi(shifts, e * 3 + 2, isb);
        float r2 = vx * vx + vy * vy + vz * vz;
        float r = sqrtf(r2);
        float rs = fmaxf(r, 1e-9f);
        float inv = 1.0f / rs;
        float Yx = vx * inv, Yy = vy * inv, Yz = vz * inv;

        // edge_feats = sqrt(2/5)*sin(q*pi*rs/5)/rs * fc(r/5)
        float x = r * 0.2f;
        float x2 = x * x, x3 = x2 * x, x6 = x3 * x3, x7 = x6 * x, x8 = x7 * x;
        float fcv = 1.f - 28.f * x6 + 48.f * x7 - 21.f * x8;
        float scl = 0.63245553203367587f * inv * fcv;
        float ang = 0.62831853071795865f * rs;   // pi/5 * rs
        float ef[8];
        #pragma unroll
        for (int q = 0; q < 8; q++) ef[q] = scl * sinf(ang * (float)(q + 1));

        // radial MLP: lane owns h2[jbase .. jbase+16)
        float h2[16];
        #pragma unroll
        for (int jj = 0; jj < 16; jj++) h2[jj] = 0.f;
        for (int k = 0; k < 64; k++) {
            float a = 0.f;
            #pragma unroll
            for (int q = 0; q < 8; q++) a += ef[q] * r1[k * 8 + q];
            float h1k = silu_f(a);
            const float4* row = (const float4*)(r2w + k * 64 + jbase);
            #pragma unroll
            for (int j4 = 0; j4 < 4; j4++) {
                float4 rv = row[j4];
                h2[j4 * 4 + 0] += h1k * rv.x;
                h2[j4 * 4 + 1] += h1k * rv.y;
                h2[j4 * 4 + 2] += h1k * rv.z;
                h2[j4 * 4 + 3] += h1k * rv.w;
            }
        }
        #pragma unroll
        for (int jj = 0; jj < 16; jj++) h2[jj] = silu_f(h2[jj]);

        #pragma unroll
        for (int c4 = 0; c4 < 8; c4++) {
            const int c0 = c4 * 4;
            float wp[5][4];
            #pragma unroll
            for (int p = 0; p < 5; p++) {
                #pragma unroll
                for (int cc = 0; cc < 4; cc++) {
                    const float4* rp4 = (const float4*)(r3l + (c0 + cc) * 320 + p * 64 + jbase);
                    float acc = 0.f;
                    #pragma unroll
                    for (int j4 = 0; j4 < 4; j4++) {
                        float4 rv = rp4[j4];
                        acc += h2[j4 * 4 + 0] * rv.x + h2[j4 * 4 + 1] * rv.y
                             + h2[j4 * 4 + 2] * rv.z + h2[j4 * 4 + 3] * rv.w;
                    }
                    // butterfly: full sum lands in ALL 4 lanes of the group
                    acc += __shfl_xor(acc, 1, 64);
                    acc += __shfl_xor(acc, 2, 64);
                    wp[p][cc] = acc;
                }
            }
            // owner lane of chunk c4 (lane c4>>1 holds channels 8l..8l+7) accumulates
            if ((c4 >> 1) == l) {
                #pragma unroll
                for (int cc = 0; cc < 4; cc++) {
                    const int ac = ((c4 & 1) << 2) | cc;   // 0..7, compile-time
                    float ss  = b2f(sraw[ac]);
                    float vvx = vr24(vraw0, vraw1, vraw2, ac * 3 + 0);
                    float vvy = vr24(vraw0, vraw1, vraw2, ac * 3 + 1);
                    float vvz = vr24(vraw0, vraw1, vraw2, ac * 3 + 2);
                    float dt = vvx * Yx + vvy * Yy + vvz * Yz;
                    float cx = vvy * Yz - vvz * Yy;
                    float cy = vvz * Yx - vvx * Yz;
                    float cz = vvx * Yy - vvy * Yx;
                    accS[ac]        += wp[0][cc] * ss + wp[3][cc] * dt;
                    accV[ac * 3 + 0] += wp[1][cc] * ss * Yx + wp[2][cc] * vvx + wp[4][cc] * cx;
                    accV[ac * 3 + 1] += wp[1][cc] * ss * Yy + wp[2][cc] * vvy + wp[4][cc] * cy;
                    accV[ac * 3 + 2] += wp[1][cc] * ss * Yz + wp[2][cc] * vvz + wp[4][cc] * cz;
                }
            }
        }
    }

    // single write per node, no atomics; lane l covers contiguous channels 8l..8l+7
    float* Sd = S + (size_t)n * 32 + 8 * l;
    float* Vd = V + (size_t)n * 96 + 24 * l;
    #pragma unroll
    for (int i = 0; i < 2; i++) {
        float4 o = { accS[i * 4 + 0] * 0.0625f, accS[i * 4 + 1] * 0.0625f,
                     accS[i * 4 + 2] * 0.0625f, accS[i * 4 + 3] * 0.0625f };
        *(float4*)(Sd + i * 4) = o;
    }
    #pragma unroll
    for (int i = 0; i < 6; i++) {
        float4 o = { accV[i * 4 + 0] * 0.0625f, accV[i * 4 + 1] * 0.0625f,
                     accV[i * 4 + 2] * 0.0625f, accV[i * 4 + 3] * 0.0625f };
        *(float4*)(Vd + i * 4) = o;
    }
}

// ---- per-node post: out/skip/product/linear, writes invariants + new s,v in-place ----
__global__ __launch_bounds__(256) void post_kernel(const float* __restrict__ Wc,
                                                   const float* __restrict__ Sb,
                                                   const float* __restrict__ Vb,
                                                   float* __restrict__ s,
                                                   bf16* __restrict__ vbst,
                                                   const int* __restrict__ spec,
                                                   float* __restrict__ out, int layer) {
    __shared__ float A_s[8][32];
    __shared__ float A_v[8][96];
    __shared__ float B_s[8][32];
    __shared__ float B_v[8][96];
    int tid = threadIdx.x;
    int nl = tid >> 5, d = tid & 31;
    int n = blockIdx.x * 8 + nl;
    A_s[nl][d]      = Sb[n * 32 + d];
    A_v[nl][d]      = Vb[n * 96 + d];
    A_v[nl][d + 32] = Vb[n * 96 + d + 32];
    A_v[nl][d + 64] = Vb[n * 96 + d + 64];
    B_s[nl][d]      = s[n * 32 + d];
    B_v[nl][d]      = (float)vbst[n * 96 + d];
    B_v[nl][d + 32] = (float)vbst[n * 96 + d + 32];
    B_v[nl][d + 64] = (float)vbst[n * 96 + d + 64];
    __syncthreads();

    int z = spec[n];
    const float* wos = Wc + OFF_OUTS + layer * 1024;
    const float* wov = Wc + OFF_OUTV + layer * 1024;
    const float* wss = Wc + OFF_SCS + (layer * Z_ + z) * 1024;
    const float* wsv = Wc + OFF_SCV + (layer * Z_ + z) * 1024;
    float s2 = 0.f, v20 = 0.f, v21 = 0.f, v22 = 0.f;
    float scs = 0.f, scv0 = 0.f, scv1 = 0.f, scv2 = 0.f;
    #pragma unroll 8
    for (int c = 0; c < 32; c++) {
        float wo = wos[c * 32 + d], wv = wov[c * 32 + d];
        float wa = wss[c * 32 + d], wb = wsv[c * 32 + d];
        s2  += A_s[nl][c] * wo;
        v20 += A_v[nl][c * 3 + 0] * wv;
        v21 += A_v[nl][c * 3 + 1] * wv;
        v22 += A_v[nl][c * 3 + 2] * wv;
        scs  += B_s[nl][c] * wa;
        scv0 += B_v[nl][c * 3 + 0] * wb;
        scv1 += B_v[nl][c * 3 + 1] * wb;
        scv2 += B_v[nl][c * 3 + 2] * wb;
    }
    const float* wp = Wc + OFF_WP + (layer * Z_ + z) * 160;
    float we0 = wp[d], we1 = wp[32 + d], we2 = wp[64 + d], we3 = wp[96 + d], we4 = wp[128 + d];
    float ps = we0 * s2 + we1 * s2 * s2 + we2 * (v20 * v20 + v21 * v21 + v22 * v22);
    float pv0 = we3 * v20 + we4 * s2 * v20;
    float pv1 = we3 * v21 + we4 * s2 * v21;
    float pv2 = we3 * v22 + we4 * s2 * v22;
    __syncthreads();
    A_s[nl][d] = ps;
    A_v[nl][d * 3 + 0] = pv0;
    A_v[nl][d * 3 + 1] = pv1;
    A_v[nl][d * 3 + 2] = pv2;
    __syncthreads();
    const float* wls = Wc + OFF_LINS + layer * 1024;
    const float* wlv = Wc + OFF_LINV + layer * 1024;
    float sn = scs, vn0 = scv0, vn1 = scv1, vn2 = scv2;
    #pragma unroll 8
    for (int c = 0; c < 32; c++) {
        float wl = wls[c * 32 + d], w2_ = wlv[c * 32 + d];
        sn  += A_s[nl][c] * wl;
        vn0 += A_v[nl][c * 3 + 0] * w2_;
        vn1 += A_v[nl][c * 3 + 1] * w2_;
        vn2 += A_v[nl][c * 3 + 2] * w2_;
    }
    s[n * 32 + d] = sn;
    out[(size_t)n * 64 + layer * 32 + d] = sn;   // fp32 output (verified round 5)
    vbst[n * 96 + d * 3 + 0] = __float2bfloat16(vn0);
    vbst[n * 96 + d * 3 + 1] = __float2bfloat16(vn1);
    vbst[n * 96 + d * 3 + 2] = __float2bfloat16(vn2);
}

// Host-side: resolve input pointers by element count (robust to harness input
// ordering). Greedy first-unused match preserves relative order within equal
// sizes, so if the harness order == reference dict order this is the identity.
static void resolve_inputs(const int* in_sizes, int n_in, int idx[17]) {
    const int want[17] = {150000, 500000, 2400000, 320, 2048, 2048, 1024, 8192,
                          20480, 2048, 2048, 20480, 20480, 3200, 2048, 2048, 1600000};
    for (int k = 0; k < 17; k++) idx[k] = k;   // default identity
    if (!in_sizes || n_in < 17) return;
    bool used[64];
    for (int i = 0; i < 64; i++) used[i] = false;
    int tmp[17];
    for (int k = 0; k < 17; k++) {
        int found = -1;
        for (int i = 0; i < n_in && i < 64; i++) {
            if (!used[i] && in_sizes[i] == want[k]) { found = i; break; }
        }
        if (found < 0) return;               // sizes don't match expectation: keep identity
        used[found] = true;
        tmp[k] = found;
    }
    for (int k = 0; k < 17; k++) idx[k] = tmp[k];
}

extern "C" void kernel_launch(void* const* d_in, const int* in_sizes, int n_in,
                              void* d_out, int out_size, void* d_ws, size_t ws_size,
                              hipStream_t stream) {
    (void)out_size; (void)ws_size;
    int idx[17];
    resolve_inputs(in_sizes, n_in, idx);

    const void* pos    = d_in[idx[0]];
    const void* attrs  = d_in[idx[1]];
    const void* shifts = d_in[idx[2]];
    const int*  ei     = (const int*)d_in[idx[16]];
    float* out = (float*)d_out;

    int*   I = (int*)d_ws;
    float* W = (float*)d_ws;

    hipMemsetAsync(I, 0, 64 * sizeof(int), stream);                             // flag + dh
    hipMemsetAsync(I + O_ROWP, 0, 50048 * sizeof(int), stream);                 // degrees
    hipMemsetAsync(W + O_VB, 0, (size_t)N_ * C_ * 3 * sizeof(bf16), stream);    // v state = 0

    detect_kernel<<<1, 256, 0, stream>>>((const unsigned*)attrs, I + O_FLAG);

    ConvArgs ca;
    for (int k = 0; k < 13; k++) ca.p[k] = d_in[idx[3 + k]];
    convert_kernel<<<(W_TOTAL + 255) / 256, 256, 0, stream>>>(ca, I + O_FLAG, W + O_W);
    posconv_kernel<<<(N_ * 3 + 255) / 256, 256, 0, stream>>>(pos, I + O_FLAG, W + O_POSF);
    spec_kernel<<<(N_ + 255) / 256, 256, 0, stream>>>(attrs, I + O_FLAG, I + O_SPEC);
    sinit_kernel<<<(N_ * C_) / 256, 256, 0, stream>>>(W + O_W, I + O_SPEC, W + O_S);

    // one-time CSR build + degree-sorted node order (graph static across layers)
    deg_kernel<<<E_ / 256, 256, 0, stream>>>(ei, W + O_POSF, shifts, I + O_FLAG, I + O_ROWP);
    scan_kernel<<<1, 1024, 0, stream>>>(I + O_ROWP);
    scatter_kernel<<<E_ / 256, 256, 0, stream>>>(ei, W + O_POSF, shifts, I + O_FLAG,
                                                 I + O_ROWP, I + O_EIDS);
    nhist_kernel<<<(N_ + 255) / 256, 256, 0, stream>>>(I + O_ROWP, I + O_DH);
    nscan_kernel<<<1, 64, 0, stream>>>(I + O_DH);
    nscatter_kernel<<<(N_ + 255) / 256, 256, 0, stream>>>(I + O_ROWP, I + O_DH, I + O_NORD);

    for (int l = 0; l < 2; l++) {
        up_kernel<<<N_ / 8, 256, 0, stream>>>(W + O_W, W + O_S, (const bf16*)(W + O_VB),
                                              (bf16*)(W + O_SUB), (bf16*)(W + O_VUB), l);
        // no SS/VV memset needed: msg_kernel writes every node exactly once
        msg_kernel<<<(N_ + 63) / 64, 256, 0, stream>>>(I + O_NORD, I + O_ROWP, I + O_EIDS,
                                                       ei, W + O_POSF, shifts, I + O_FLAG,
                                                       W + O_W,
                                                       (const bf16*)(W + O_SUB),
                                                       (const bf16*)(W + O_VUB),
                                                       W + O_SS, W + O_VV, l);
        post_kernel<<<N_ / 8, 256, 0, stream>>>(W + O_W, W + O_SS, W + O_VV,
                                                W + O_S, (bf16*)(W + O_VB),
                                                I + O_SPEC, out, l);
    }
}

// Round 2
// 14024.135 us; speedup vs baseline: 1.1342x; 1.1342x over previous
//
#include <hip/hip_runtime.h>
#include <hip/hip_bf16.h>

typedef __hip_bfloat16 bf16;
typedef __attribute__((ext_vector_type(8))) unsigned short us8;

// Problem constants
constexpr int N_ = 50000;
constexpr int E_ = 800000;
constexpr int C_ = 32;
constexpr int Z_ = 10;

// fp32 weight arena offsets (floats)
constexpr int OFF_EMB  = 0;                    // [Z][C]          320
constexpr int OFF_UPS  = 320;                  // [L][C][C]       2048
constexpr int OFF_UPV  = OFF_UPS + 2048;       // [L][C][C]       2048
constexpr int OFF_R1T  = OFF_UPV + 2048;       // [L][64][8]  (transposed)  1024
constexpr int OFF_R2   = OFF_R1T + 1024;       // [L][64][64]     8192
constexpr int OFF_R3T  = OFF_R2 + 8192;        // [L][32][5][64] (c-major) 20480
constexpr int OFF_OUTS = OFF_R3T + 20480;      // [L][C][C]       2048
constexpr int OFF_OUTV = OFF_OUTS + 2048;      // [L][C][C]       2048
constexpr int OFF_SCS  = OFF_OUTV + 2048;      // [L][Z][C][C]    20480
constexpr int OFF_SCV  = OFF_SCS + 20480;      // [L][Z][C][C]    20480
constexpr int OFF_WP   = OFF_SCV + 20480;      // [L][Z][5][C]    3200
constexpr int OFF_LINS = OFF_WP + 3200;        // [L][C][C]       2048
constexpr int OFF_LINV = OFF_LINS + 2048;      // [L][C][C]       2048
constexpr int W_TOTAL  = OFF_LINV + 2048;      // 86464

// workspace layout, in 4-byte words. Total 14,786,688 words = 56.41 MiB
constexpr size_t O_CNT  = 0;                   // int (unused, kept)
constexpr size_t O_FLAG = 1;                   // int: 1 => float inputs are bf16
constexpr size_t O_DH   = 8;                   // 48 ints: degree histogram/base (inside zeroed 64)
constexpr size_t O_SPEC = 64;                  // N ints (padded 50048)
constexpr size_t O_EIDS = 50112;               // E ints: CSR-ordered active edge ids
constexpr size_t O_POSF = 850112;              // N*3 fp32 (padded 150016)
constexpr size_t O_W    = 1000128;             // W_TOTAL fp32
constexpr size_t O_S    = 1086592;             // N*C fp32 (state s)
constexpr size_t O_VB   = 2686592;             // N*C*3 bf16 (state v, 2400000 words)
constexpr size_t O_SUB  = 5086592;             // N*C bf16   (800000 words)
constexpr size_t O_VUB  = 5886592;             // N*C*3 bf16 (2400000 words)
constexpr size_t O_SS   = 8286592;             // N*C fp32   (S accum)
constexpr size_t O_VV   = 9886592;             // N*C*3 fp32 (V accum) -> ends 14686592
constexpr size_t O_ROWP = 14686592;            // N ints (padded 50048): rowptr (destructive-scan)
constexpr size_t O_NORD = 14736640;            // N ints (padded 50048): degree-sorted node order

struct ConvArgs { const void* p[13]; };

// dual-dtype input load: isb is wave-uniform => scalar branch
__device__ __forceinline__ float ldi(const void* p, int i, int isb) {
    if (isb) return (float)((const bf16*)p)[i];
    return ((const float*)p)[i];
}
__device__ __forceinline__ float b2f(unsigned short u) {   // bf16 bits -> float
    union { unsigned x; float f; } v; v.x = ((unsigned)u) << 16; return v.f;
}
// element i (0..23) of a 24-ushort row held as three us8 (i must fold to constant)
__device__ __forceinline__ float vr24(const us8 a, const us8 b, const us8 c, int i) {
    unsigned short u = (i < 8) ? a[i & 7] : (i < 16) ? b[i & 7] : c[i & 7];
    return b2f(u);
}

// ---- dtype detection on node_attrs (one-hot): word 0x00003F80 occurs only if bf16 ----
__global__ __launch_bounds__(256) void detect_kernel(const unsigned* __restrict__ a,
                                                     int* __restrict__ flag) {
    int t = threadIdx.x;
    int hit = 0;
    for (int i = t; i < 4096; i += 256) hit |= (a[i] == 0x00003F80u) ? 1 : 0;
    if (hit) atomicOr(flag, 1);
}

// ---- weight conversion (-> fp32, with R1/R3 transposes) ----
__global__ __launch_bounds__(256) void convert_kernel(ConvArgs a, const int* __restrict__ flag,
                                                      float* __restrict__ Wc) {
    int t = blockIdx.x * 256 + threadIdx.x;
    if (t >= W_TOTAL) return;
    int isb = *flag;
    int u = t;
    if (u < 320)  { Wc[OFF_EMB + u] = ldi(a.p[0], u, isb); return; }  u -= 320;
    if (u < 2048) { Wc[OFF_UPS + u] = ldi(a.p[1], u, isb); return; }  u -= 2048;
    if (u < 2048) { Wc[OFF_UPV + u] = ldi(a.p[2], u, isb); return; }  u -= 2048;
    if (u < 1024) {                       // R1 [L][8][64] -> R1T [L][64][8]
        int l = u >> 9, r = u & 511, j = r >> 3, k = r & 7;
        Wc[OFF_R1T + u] = ldi(a.p[3], l * 512 + k * 64 + j, isb); return;
    }  u -= 1024;
    if (u < 8192) { Wc[OFF_R2 + u] = ldi(a.p[4], u, isb); return; }   u -= 8192;
    if (u < 20480) {                      // R3 [L][64][160] -> R3T [L][32][5][64] (c-major)
        int l = u / 10240, r = u % 10240, c = r / 320, r2 = r % 320, p = r2 / 64, j = r2 % 64;
        Wc[OFF_R3T + u] = ldi(a.p[5], l * 10240 + j * 160 + p * 32 + c, isb); return;
    }  u -= 20480;
    if (u < 2048)  { Wc[OFF_OUTS + u] = ldi(a.p[6], u, isb);  return; } u -= 2048;
    if (u < 2048)  { Wc[OFF_OUTV + u] = ldi(a.p[7], u, isb);  return; } u -= 2048;
    if (u < 20480) { Wc[OFF_SCS  + u] = ldi(a.p[8], u, isb);  return; } u -= 20480;
    if (u < 20480) { Wc[OFF_SCV  + u] = ldi(a.p[9], u, isb);  return; } u -= 20480;
    if (u < 3200)  { Wc[OFF_WP   + u] = ldi(a.p[10], u, isb); return; } u -= 3200;
    if (u < 2048)  { Wc[OFF_LINS + u] = ldi(a.p[11], u, isb); return; } u -= 2048;
    Wc[OFF_LINV + u] = ldi(a.p[12], u, isb);
}

// ---- positions -> fp32 ----
__global__ __launch_bounds__(256) void posconv_kernel(const void* __restrict__ pos,
                                                      const int* __restrict__ flag,
                                                      float* __restrict__ posf) {
    int t = blockIdx.x * 256 + threadIdx.x;
    if (t >= N_ * 3) return;
    posf[t] = ldi(pos, t, *flag);
}

// ---- species from one-hot ----
__global__ __launch_bounds__(256) void spec_kernel(const void* __restrict__ attrs,
                                                   const int* __restrict__ flag,
                                                   int* __restrict__ spec) {
    int n = blockIdx.x * 256 + threadIdx.x;
    if (n >= N_) return;
    int isb = *flag;
    int z = 0;
    #pragma unroll
    for (int zz = 0; zz < Z_; zz++)
        if (ldi(attrs, n * Z_ + zz, isb) > 0.5f) z = zz;
    spec[n] = z;
}

// ---- s init: s[n][c] = W_embed[spec[n]][c] ----
__global__ __launch_bounds__(256) void sinit_kernel(const float* __restrict__ Wc,
                                                    const int* __restrict__ spec,
                                                    float* __restrict__ s) {
    int t = blockIdx.x * 256 + threadIdx.x;   // N*C threads
    int n = t >> 5, c = t & 31;
    s[t] = Wc[OFF_EMB + spec[n] * C_ + c];
}

// ---- CSR build step 1: per-dst degree of ACTIVE edges (r < RCUT) ----
__global__ __launch_bounds__(256) void deg_kernel(const int* __restrict__ ei,
                                                  const float* __restrict__ posf,
                                                  const void* __restrict__ shifts,
                                                  const int* __restrict__ flag,
                                                  int* __restrict__ rp) {
    int e = blockIdx.x * 256 + threadIdx.x;
    int isb = *flag;
    int s = ei[e], d = ei[E_ + e];
    if (s < 0 || s >= N_ || d < 0 || d >= N_) return;
    float vx = posf[d * 3 + 0] - posf[s * 3 + 0] + ldi(shifts, e * 3 + 0, isb);
    float vy = posf[d * 3 + 1] - posf[s * 3 + 1] + ldi(shifts, e * 3 + 1, isb);
    float vz = posf[d * 3 + 2] - posf[s * 3 + 2] + ldi(shifts, e * 3 + 2, isb);
    if (vx * vx + vy * vy + vz * vz < 25.0f) atomicAdd(rp + d, 1);
}

// ---- CSR build step 2: in-place exclusive prefix sum over rp[0..N) ----
__global__ __launch_bounds__(1024) void scan_kernel(int* __restrict__ rp) {
    __shared__ int ps[1024];
    int t = threadIdx.x;
    constexpr int CH = (N_ + 1023) / 1024;   // 49
    int base = t * CH;
    int sum = 0;
    for (int i = 0; i < CH; i++) {
        int idx = base + i;
        if (idx < N_) sum += rp[idx];
    }
    ps[t] = sum;
    __syncthreads();
    for (int off = 1; off < 1024; off <<= 1) {
        int v = (t >= off) ? ps[t - off] : 0;
        __syncthreads();
        ps[t] += v;
        __syncthreads();
    }
    int run = (t == 0) ? 0 : ps[t - 1];
    for (int i = 0; i < CH; i++) {
        int idx = base + i;
        if (idx < N_) { int v = rp[idx]; rp[idx] = run; run += v; }
    }
}

// ---- CSR build step 3: scatter edge ids (destructive: rp becomes INCLUSIVE prefix) ----
__global__ __launch_bounds__(256) void scatter_kernel(const int* __restrict__ ei,
                                                      const float* __restrict__ posf,
                                                      const void* __restrict__ shifts,
                                                      const int* __restrict__ flag,
                                                      int* __restrict__ rp,
                                                      int* __restrict__ csr) {
    int e = blockIdx.x * 256 + threadIdx.x;
    int isb = *flag;
    int s = ei[e], d = ei[E_ + e];
    if (s < 0 || s >= N_ || d < 0 || d >= N_) return;
    float vx = posf[d * 3 + 0] - posf[s * 3 + 0] + ldi(shifts, e * 3 + 0, isb);
    float vy = posf[d * 3 + 1] - posf[s * 3 + 1] + ldi(shifts, e * 3 + 1, isb);
    float vz = posf[d * 3 + 2] - posf[s * 3 + 2] + ldi(shifts, e * 3 + 2, isb);
    if (vx * vx + vy * vy + vz * vz < 25.0f) {
        int pos = atomicAdd(rp + d, 1);
        csr[pos] = e;
    }
}

// ---- node degree-sort (counting sort, 48 bins, heavy-first) for wave load balance ----
__global__ __launch_bounds__(256) void nhist_kernel(const int* __restrict__ rp,
                                                    int* __restrict__ dh) {
    int n = blockIdx.x * 256 + threadIdx.x;
    if (n >= N_) return;
    int deg = rp[n] - (n ? rp[n - 1] : 0);
    atomicAdd(dh + (47 - min(deg, 47)), 1);
}
__global__ void nscan_kernel(int* __restrict__ dh) {
    if (threadIdx.x == 0) {
        int run = 0;
        for (int i = 0; i < 48; i++) { int v = dh[i]; dh[i] = run; run += v; }
    }
}
__global__ __launch_bounds__(256) void nscatter_kernel(const int* __restrict__ rp,
                                                       int* __restrict__ dh,
                                                       int* __restrict__ nord) {
    int n = blockIdx.x * 256 + threadIdx.x;
    if (n >= N_) return;
    int deg = rp[n] - (n ? rp[n - 1] : 0);
    int pos = atomicAdd(dh + (47 - min(deg, 47)), 1);
    nord[pos] = n;
}

// ---- per-node "up" linear: su = s@Wus, vu = v@Wuv (fp32 math, bf16 outs) ----
__global__ __launch_bounds__(256) void up_kernel(const float* __restrict__ Wc,
                                                 const float* __restrict__ s,
                                                 const bf16* __restrict__ vb,
                                                 bf16* __restrict__ su,
                                                 bf16* __restrict__ vu, int layer) {
    __shared__ float s_sh[8][32];
    __shared__ float v_sh[8][96];
    int tid = threadIdx.x;
    int nl = tid >> 5, d = tid & 31;
    int n = blockIdx.x * 8 + nl;
    s_sh[nl][d]      = s[n * 32 + d];
    v_sh[nl][d]      = (float)vb[n * 96 + d];
    v_sh[nl][d + 32] = (float)vb[n * 96 + d + 32];
    v_sh[nl][d + 64] = (float)vb[n * 96 + d + 64];
    __syncthreads();
    const float* wus = Wc + OFF_UPS + layer * 1024;
    const float* wuv = Wc + OFF_UPV + layer * 1024;
    float a0 = 0.f, b0 = 0.f, b1 = 0.f, b2 = 0.f;
    #pragma unroll 8
    for (int c = 0; c < 32; c++) {
        float wS = wus[c * 32 + d], wV = wuv[c * 32 + d];
        a0 += s_sh[nl][c] * wS;
        b0 += v_sh[nl][c * 3 + 0] * wV;
        b1 += v_sh[nl][c * 3 + 1] * wV;
        b2 += v_sh[nl][c * 3 + 2] * wV;
    }
    su[n * 32 + d] = __float2bfloat16(a0);
    vu[n * 96 + d * 3 + 0] = __float2bfloat16(b0);
    vu[n * 96 + d * 3 + 1] = __float2bfloat16(b1);
    vu[n * 96 + d * 3 + 2] = __float2bfloat16(b2);
}

__device__ __forceinline__ float silu_f(float a) {
    return a / (1.f + __expf(-a));
}

// ---- fused edge kernel, DST-PARALLEL over CSR: one 4-lane group per node ----
// Round-1 lesson (rocprof): __launch_bounds__(256,4) capped VGPRs at 64 while the
// persistent accS/accV + raw gathers need ~100 -> everything (notably h2[16])
// spilled to scratch; the R3 dots re-read h2 from scratch = 9.4 GB of HBM
// traffic (FETCH_SIZE 7.4e6 KB) and VALUBusy 1.9%. Fixes:
//  (a) default VGPR budget (no min-waves hint) — grid gives only ~3 waves/SIMD
//      anyway, spill-freedom beats occupancy here;
//  (b) R3 path weights computed per-CHANNEL (wpp[5], butterfly+use immediately)
//      instead of per-chunk wp[5][4] — 15 fewer live regs at peak.
__global__ __launch_bounds__(256) void msg_kernel(const int* __restrict__ nord,
                                                  const int* __restrict__ rowp,
                                                  const int* __restrict__ csr,
                                                  const int* __restrict__ ei,
                                                  const float* __restrict__ posf,
                                                  const void* __restrict__ shifts,
                                                  const int* __restrict__ flag,
                                                  const float* __restrict__ Wc,
                                                  const bf16* __restrict__ sub,
                                                  const bf16* __restrict__ vub,
                                                  float* __restrict__ S,
                                                  float* __restrict__ V, int layer) {
    int tid = threadIdx.x;
    int lane = tid & 63;
    int g = lane >> 2, l = lane & 3;
    int gi = blockIdx.x * 64 + (tid >> 6) * 16 + g;
    if (gi >= N_) return;
    int n = nord[gi];
    int beg = (n == 0) ? 0 : rowp[n - 1];   // rowp is inclusive prefix post-scatter
    int end = rowp[n];
    int isb = *flag;
    float dpx = posf[n * 3 + 0], dpy = posf[n * 3 + 1], dpz = posf[n * 3 + 2];
    const int jbase = l * 16;
    const float* r1  = Wc + OFF_R1T + layer * 512;   // [64][8]
    const float* r2w = Wc + OFF_R2  + layer * 4096;  // [64][64]
    const float* r3l = Wc + OFF_R3T + layer * 10240; // [32][5][64] c-major

    float accS[8], accV[24];
    #pragma unroll
    for (int i = 0; i < 8; i++) accS[i] = 0.f;
    #pragma unroll
    for (int i = 0; i < 24; i++) accV[i] = 0.f;

    for (int idx = beg; idx < end; idx++) {
        int e = csr[idx];
        int srcn = ei[e];
        // coalesced row gathers: group of 4 lanes reads the full src row
        us8 sraw = *(const us8*)((const unsigned short*)sub + (size_t)srcn * 32 + 8 * l);
        const unsigned short* vrow = (const unsigned short*)vub + (size_t)srcn * 96 + 24 * l;
        us8 vraw0 = *(const us8*)(vrow);
        us8 vraw1 = *(const us8*)(vrow + 8);
        us8 vraw2 = *(const us8*)(vrow + 16);

        float vx = dpx - posf[srcn * 3 + 0] + ldi(shifts, e * 3 + 0, isb);
        float vy = dpy - posf[srcn * 3 + 1] + ldi(shifts, e * 3 + 1, isb);
        float vz = dpz - posf[srcn * 3 + 2] + ldi(shifts, e * 3 + 2, isb);
        float r2 = vx * vx + vy * vy + vz * vz;
        float r = sqrtf(r2);
        float rs = fmaxf(r, 1e-9f);
        float inv = 1.0f / rs;
        float Yx = vx * inv, Yy = vy * inv, Yz = vz * inv;

        // edge_feats = sqrt(2/5)*sin(q*pi*rs/5)/rs * fc(r/5)
        float x = r * 0.2f;
        float x2 = x * x, x3 = x2 * x, x6 = x3 * x3, x7 = x6 * x, x8 = x7 * x;
        float fcv = 1.f - 28.f * x6 + 48.f * x7 - 21.f * x8;
        float scl = 0.63245553203367587f * inv * fcv;
        float ang = 0.62831853071795865f * rs;   // pi/5 * rs
        float ef[8];
        #pragma unroll
        for (int q = 0; q < 8; q++) ef[q] = scl * sinf(ang * (float)(q + 1));

        // radial MLP: lane owns h2[jbase .. jbase+16)
        float h2[16];
        #pragma unroll
        for (int jj = 0; jj < 16; jj++) h2[jj] = 0.f;
        for (int k = 0; k < 64; k++) {
            float a = 0.f;
            #pragma unroll
            for (int q = 0; q < 8; q++) a += ef[q] * r1[k * 8 + q];
            float h1k = silu_f(a);
            const float4* row = (const float4*)(r2w + k * 64 + jbase);
            #pragma unroll
            for (int j4 = 0; j4 < 4; j4++) {
                float4 rv = row[j4];
                h2[j4 * 4 + 0] += h1k * rv.x;
                h2[j4 * 4 + 1] += h1k * rv.y;
                h2[j4 * 4 + 2] += h1k * rv.z;
                h2[j4 * 4 + 3] += h1k * rv.w;
            }
        }
        #pragma unroll
        for (int jj = 0; jj < 16; jj++) h2[jj] = silu_f(h2[jj]);

        // R3 + message, one channel at a time (wpp[5] live, not wp[5][4])
        #pragma unroll
        for (int c4 = 0; c4 < 8; c4++) {
            const int c0 = c4 * 4;
            #pragma unroll
            for (int cc = 0; cc < 4; cc++) {
                float wpp[5];
                #pragma unroll
                for (int p = 0; p < 5; p++) {
                    const float4* rp4 = (const float4*)(r3l + (c0 + cc) * 320 + p * 64 + jbase);
                    float acc = 0.f;
                    #pragma unroll
                    for (int j4 = 0; j4 < 4; j4++) {
                        float4 rv = rp4[j4];
                        acc += h2[j4 * 4 + 0] * rv.x + h2[j4 * 4 + 1] * rv.y
                             + h2[j4 * 4 + 2] * rv.z + h2[j4 * 4 + 3] * rv.w;
                    }
                    // butterfly: full sum lands in ALL 4 lanes of the group
                    acc += __shfl_xor(acc, 1, 64);
                    acc += __shfl_xor(acc, 2, 64);
                    wpp[p] = acc;
                }
                // owner lane of chunk c4 (lane c4>>1 holds channels 8l..8l+7)
                if ((c4 >> 1) == l) {
                    const int ac = ((c4 & 1) << 2) | cc;   // 0..7, compile-time
                    float ss  = b2f(sraw[ac]);
                    float vvx = vr24(vraw0, vraw1, vraw2, ac * 3 + 0);
                    float vvy = vr24(vraw0, vraw1, vraw2, ac * 3 + 1);
                    float vvz = vr24(vraw0, vraw1, vraw2, ac * 3 + 2);
                    float dt = vvx * Yx + vvy * Yy + vvz * Yz;
                    float cx = vvy * Yz - vvz * Yy;
                    float cy = vvz * Yx - vvx * Yz;
                    float cz = vvx * Yy - vvy * Yx;
                    accS[ac]         += wpp[0] * ss + wpp[3] * dt;
                    accV[ac * 3 + 0] += wpp[1] * ss * Yx + wpp[2] * vvx + wpp[4] * cx;
                    accV[ac * 3 + 1] += wpp[1] * ss * Yy + wpp[2] * vvy + wpp[4] * cy;
                    accV[ac * 3 + 2] += wpp[1] * ss * Yz + wpp[2] * vvz + wpp[4] * cz;
                }
            }
        }
    }

    // single write per node, no atomics; lane l covers contiguous channels 8l..8l+7
    float* Sd = S + (size_t)n * 32 + 8 * l;
    float* Vd = V + (size_t)n * 96 + 24 * l;
    #pragma unroll
    for (int i = 0; i < 2; i++) {
        float4 o = { accS[i * 4 + 0] * 0.0625f, accS[i * 4 + 1] * 0.0625f,
                     accS[i * 4 + 2] * 0.0625f, accS[i * 4 + 3] * 0.0625f };
        *(float4*)(Sd + i * 4) = o;
    }
    #pragma unroll
    for (int i = 0; i < 6; i++) {
        float4 o = { accV[i * 4 + 0] * 0.0625f, accV[i * 4 + 1] * 0.0625f,
                     accV[i * 4 + 2] * 0.0625f, accV[i * 4 + 3] * 0.0625f };
        *(float4*)(Vd + i * 4) = o;
    }
}

// ---- per-node post: out/skip/product/linear, writes invariants + new s,v in-place ----
__global__ __launch_bounds__(256) void post_kernel(const float* __restrict__ Wc,
                                                   const float* __restrict__ Sb,
                                                   const float* __restrict__ Vb,
                                                   float* __restrict__ s,
                                                   bf16* __restrict__ vbst,
                                                   const int* __restrict__ spec,
                                                   float* __restrict__ out, int layer) {
    __shared__ float A_s[8][32];
    __shared__ float A_v[8][96];
    __shared__ float B_s[8][32];
    __shared__ float B_v[8][96];
    int tid = threadIdx.x;
    int nl = tid >> 5, d = tid & 31;
    int n = blockIdx.x * 8 + nl;
    A_s[nl][d]      = Sb[n * 32 + d];
    A_v[nl][d]      = Vb[n * 96 + d];
    A_v[nl][d + 32] = Vb[n * 96 + d + 32];
    A_v[nl][d + 64] = Vb[n * 96 + d + 64];
    B_s[nl][d]      = s[n * 32 + d];
    B_v[nl][d]      = (float)vbst[n * 96 + d];
    B_v[nl][d + 32] = (float)vbst[n * 96 + d + 32];
    B_v[nl][d + 64] = (float)vbst[n * 96 + d + 64];
    __syncthreads();

    int z = spec[n];
    const float* wos = Wc + OFF_OUTS + layer * 1024;
    const float* wov = Wc + OFF_OUTV + layer * 1024;
    const float* wss = Wc + OFF_SCS + (layer * Z_ + z) * 1024;
    const float* wsv = Wc + OFF_SCV + (layer * Z_ + z) * 1024;
    float s2 = 0.f, v20 = 0.f, v21 = 0.f, v22 = 0.f;
    float scs = 0.f, scv0 = 0.f, scv1 = 0.f, scv2 = 0.f;
    #pragma unroll 8
    for (int c = 0; c < 32; c++) {
        float wo = wos[c * 32 + d], wv = wov[c * 32 + d];
        float wa = wss[c * 32 + d], wb = wsv[c * 32 + d];
        s2  += A_s[nl][c] * wo;
        v20 += A_v[nl][c * 3 + 0] * wv;
        v21 += A_v[nl][c * 3 + 1] * wv;
        v22 += A_v[nl][c * 3 + 2] * wv;
        scs  += B_s[nl][c] * wa;
        scv0 += B_v[nl][c * 3 + 0] * wb;
        scv1 += B_v[nl][c * 3 + 1] * wb;
        scv2 += B_v[nl][c * 3 + 2] * wb;
    }
    const float* wp = Wc + OFF_WP + (layer * Z_ + z) * 160;
    float we0 = wp[d], we1 = wp[32 + d], we2 = wp[64 + d], we3 = wp[96 + d], we4 = wp[128 + d];
    float ps = we0 * s2 + we1 * s2 * s2 + we2 * (v20 * v20 + v21 * v21 + v22 * v22);
    float pv0 = we3 * v20 + we4 * s2 * v20;
    float pv1 = we3 * v21 + we4 * s2 * v21;
    float pv2 = we3 * v22 + we4 * s2 * v22;
    __syncthreads();
    A_s[nl][d] = ps;
    A_v[nl][d * 3 + 0] = pv0;
    A_v[nl][d * 3 + 1] = pv1;
    A_v[nl][d * 3 + 2] = pv2;
    __syncthreads();
    const float* wls = Wc + OFF_LINS + layer * 1024;
    const float* wlv = Wc + OFF_LINV + layer * 1024;
    float sn = scs, vn0 = scv0, vn1 = scv1, vn2 = scv2;
    #pragma unroll 8
    for (int c = 0; c < 32; c++) {
        float wl = wls[c * 32 + d], w2_ = wlv[c * 32 + d];
        sn  += A_s[nl][c] * wl;
        vn0 += A_v[nl][c * 3 + 0] * w2_;
        vn1 += A_v[nl][c * 3 + 1] * w2_;
        vn2 += A_v[nl][c * 3 + 2] * w2_;
    }
    s[n * 32 + d] = sn;
    out[(size_t)n * 64 + layer * 32 + d] = sn;   // fp32 output (verified round 5)
    vbst[n * 96 + d * 3 + 0] = __float2bfloat16(vn0);
    vbst[n * 96 + d * 3 + 1] = __float2bfloat16(vn1);
    vbst[n * 96 + d * 3 + 2] = __float2bfloat16(vn2);
}

// Host-side: resolve input pointers by element count (robust to harness input
// ordering). Greedy first-unused match preserves relative order within equal
// sizes, so if the harness order == reference dict order this is the identity.
static void resolve_inputs(const int* in_sizes, int n_in, int idx[17]) {
    const int want[17] = {150000, 500000, 2400000, 320, 2048, 2048, 1024, 8192,
                          20480, 2048, 2048, 20480, 20480, 3200, 2048, 2048, 1600000};
    for (int k = 0; k < 17; k++) idx[k] = k;   // default identity
    if (!in_sizes || n_in < 17) return;
    bool used[64];
    for (int i = 0; i < 64; i++) used[i] = false;
    int tmp[17];
    for (int k = 0; k < 17; k++) {
        int found = -1;
        for (int i = 0; i < n_in && i < 64; i++) {
            if (!used[i] && in_sizes[i] == want[k]) { found = i; break; }
        }
        if (found < 0) return;               // sizes don't match expectation: keep identity
        used[found] = true;
        tmp[k] = found;
    }
    for (int k = 0; k < 17; k++) idx[k] = tmp[k];
}

extern "C" void kernel_launch(void* const* d_in, const int* in_sizes, int n_in,
                              void* d_out, int out_size, void* d_ws, size_t ws_size,
                              hipStream_t stream) {
    (void)out_size; (void)ws_size;
    int idx[17];
    resolve_inputs(in_sizes, n_in, idx);

    const void* pos    = d_in[idx[0]];
    const void* attrs  = d_in[idx[1]];
    const void* shifts = d_in[idx[2]];
    const int*  ei     = (const int*)d_in[idx[16]];
    float* out = (float*)d_out;

    int*   I = (int*)d_ws;
    float* W = (float*)d_ws;

    hipMemsetAsync(I, 0, 64 * sizeof(int), stream);                             // flag + dh
    hipMemsetAsync(I + O_ROWP, 0, 50048 * sizeof(int), stream);                 // degrees
    hipMemsetAsync(W + O_VB, 0, (size_t)N_ * C_ * 3 * sizeof(bf16), stream);    // v state = 0

    detect_kernel<<<1, 256, 0, stream>>>((const unsigned*)attrs, I + O_FLAG);

    ConvArgs ca;
    for (int k = 0; k < 13; k++) ca.p[k] = d_in[idx[3 + k]];
    convert_kernel<<<(W_TOTAL + 255) / 256, 256, 0, stream>>>(ca, I + O_FLAG, W + O_W);
    posconv_kernel<<<(N_ * 3 + 255) / 256, 256, 0, stream>>>(pos, I + O_FLAG, W + O_POSF);
    spec_kernel<<<(N_ + 255) / 256, 256, 0, stream>>>(attrs, I + O_FLAG, I + O_SPEC);
    sinit_kernel<<<(N_ * C_) / 256, 256, 0, stream>>>(W + O_W, I + O_SPEC, W + O_S);

    // one-time CSR build + degree-sorted node order (graph static across layers)
    deg_kernel<<<E_ / 256, 256, 0, stream>>>(ei, W + O_POSF, shifts, I + O_FLAG, I + O_ROWP);
    scan_kernel<<<1, 1024, 0, stream>>>(I + O_ROWP);
    scatter_kernel<<<E_ / 256, 256, 0, stream>>>(ei, W + O_POSF, shifts, I + O_FLAG,
                                                 I + O_ROWP, I + O_EIDS);
    nhist_kernel<<<(N_ + 255) / 256, 256, 0, stream>>>(I + O_ROWP, I + O_DH);
    nscan_kernel<<<1, 64, 0, stream>>>(I + O_DH);
    nscatter_kernel<<<(N_ + 255) / 256, 256, 0, stream>>>(I + O_ROWP, I + O_DH, I + O_NORD);

    for (int l = 0; l < 2; l++) {
        up_kernel<<<N_ / 8, 256, 0, stream>>>(W + O_W, W + O_S, (const bf16*)(W + O_VB),
                                              (bf16*)(W + O_SUB), (bf16*)(W + O_VUB), l);
        // no SS/VV memset needed: msg_kernel writes every node exactly once
        msg_kernel<<<(N_ + 63) / 64, 256, 0, stream>>>(I + O_NORD, I + O_ROWP, I + O_EIDS,
                                                       ei, W + O_POSF, shifts, I + O_FLAG,
                                                       W + O_W,
                                                       (const bf16*)(W + O_SUB),
                                                       (const bf16*)(W + O_VUB),
                                                       W + O_SS, W + O_VV, l);
        post_kernel<<<N_ / 8, 256, 0, stream>>>(W + O_W, W + O_SS, W + O_VV,
                                                W + O_S, (bf16*)(W + O_VB),
                                                I + O_SPEC, out, l);
    }
}

// Round 3
// 1914.302 us; speedup vs baseline: 8.3091x; 7.3260x over previous
//
#include <hip/hip_runtime.h>
#include <hip/hip_bf16.h>

typedef __hip_bfloat16 bf16;

// Problem constants
constexpr int N_ = 50000;
constexpr int E_ = 800000;
constexpr int C_ = 32;
constexpr int Z_ = 10;

// fp32 weight arena offsets (floats)
constexpr int OFF_EMB  = 0;                    // [Z][C]          320
constexpr int OFF_UPS  = 320;                  // [L][C][C]       2048
constexpr int OFF_UPV  = OFF_UPS + 2048;       // [L][C][C]       2048
constexpr int OFF_R1T  = OFF_UPV + 2048;       // [L][64][8]  (transposed)  1024
constexpr int OFF_R2   = OFF_R1T + 1024;       // [L][64][64]     8192
constexpr int OFF_R3T  = OFF_R2 + 8192;        // [L][32][5][64] (c-major) 20480
constexpr int OFF_OUTS = OFF_R3T + 20480;      // [L][C][C]       2048
constexpr int OFF_OUTV = OFF_OUTS + 2048;      // [L][C][C]       2048
constexpr int OFF_SCS  = OFF_OUTV + 2048;      // [L][Z][C][C]    20480
constexpr int OFF_SCV  = OFF_SCS + 20480;      // [L][Z][C][C]    20480
constexpr int OFF_WP   = OFF_SCV + 20480;      // [L][Z][5][C]    3200
constexpr int OFF_LINS = OFF_WP + 3200;        // [L][C][C]       2048
constexpr int OFF_LINV = OFF_LINS + 2048;      // [L][C][C]       2048
constexpr int W_TOTAL  = OFF_LINV + 2048;      // 86464

// workspace layout, in 4-byte words. Total 14,786,688 words = 56.41 MiB (proven r1-r2)
constexpr size_t O_CNT  = 0;                   // int: active edge count (written by scan)
constexpr size_t O_FLAG = 1;                   // int: 1 => float inputs are bf16
constexpr size_t O_SPEC = 64;                  // N ints (padded 50048)
constexpr size_t O_EIDS = 50112;               // E ints: dst-sorted active edge ids
constexpr size_t O_POSF = 850112;              // N*3 fp32 (padded 150016)
constexpr size_t O_W    = 1000128;             // W_TOTAL fp32
constexpr size_t O_S    = 1086592;             // N*C fp32 (state s)
constexpr size_t O_VB   = 2686592;             // N*C*3 bf16 (state v, 2400000 words)
constexpr size_t O_SUB  = 5086592;             // N*C bf16   (800000 words)
constexpr size_t O_VUB  = 5886592;             // N*C*3 bf16 (2400000 words)
constexpr size_t O_SS   = 8286592;             // N*C fp32   (S accum)
constexpr size_t O_VV   = 9886592;             // N*C*3 fp32 (V accum) -> ends 14686592
constexpr size_t O_ROWP = 14686592;            // N ints (padded 50048): rowptr (destructive)

struct ConvArgs { const void* p[13]; };

// dual-dtype input load: isb is wave-uniform => scalar branch
__device__ __forceinline__ float ldi(const void* p, int i, int isb) {
    if (isb) return (float)((const bf16*)p)[i];
    return ((const float*)p)[i];
}
__device__ __forceinline__ float b2f(unsigned short u) {   // bf16 bits -> float
    union { unsigned x; float f; } v; v.x = ((unsigned)u) << 16; return v.f;
}

// ---- dtype detection on node_attrs (one-hot): word 0x00003F80 occurs only if bf16 ----
__global__ __launch_bounds__(256) void detect_kernel(const unsigned* __restrict__ a,
                                                     int* __restrict__ flag) {
    int t = threadIdx.x;
    int hit = 0;
    for (int i = t; i < 4096; i += 256) hit |= (a[i] == 0x00003F80u) ? 1 : 0;
    if (hit) atomicOr(flag, 1);
}

// ---- weight conversion (-> fp32, with R1/R3 transposes) ----
__global__ __launch_bounds__(256) void convert_kernel(ConvArgs a, const int* __restrict__ flag,
                                                      float* __restrict__ Wc) {
    int t = blockIdx.x * 256 + threadIdx.x;
    if (t >= W_TOTAL) return;
    int isb = *flag;
    int u = t;
    if (u < 320)  { Wc[OFF_EMB + u] = ldi(a.p[0], u, isb); return; }  u -= 320;
    if (u < 2048) { Wc[OFF_UPS + u] = ldi(a.p[1], u, isb); return; }  u -= 2048;
    if (u < 2048) { Wc[OFF_UPV + u] = ldi(a.p[2], u, isb); return; }  u -= 2048;
    if (u < 1024) {                       // R1 [L][8][64] -> R1T [L][64][8]
        int l = u >> 9, r = u & 511, j = r >> 3, k = r & 7;
        Wc[OFF_R1T + u] = ldi(a.p[3], l * 512 + k * 64 + j, isb); return;
    }  u -= 1024;
    if (u < 8192) { Wc[OFF_R2 + u] = ldi(a.p[4], u, isb); return; }   u -= 8192;
    if (u < 20480) {                      // R3 [L][64][160] -> R3T [L][32][5][64] (c-major)
        int l = u / 10240, r = u % 10240, c = r / 320, r2 = r % 320, p = r2 / 64, j = r2 % 64;
        Wc[OFF_R3T + u] = ldi(a.p[5], l * 10240 + j * 160 + p * 32 + c, isb); return;
    }  u -= 20480;
    if (u < 2048)  { Wc[OFF_OUTS + u] = ldi(a.p[6], u, isb);  return; } u -= 2048;
    if (u < 2048)  { Wc[OFF_OUTV + u] = ldi(a.p[7], u, isb);  return; } u -= 2048;
    if (u < 20480) { Wc[OFF_SCS  + u] = ldi(a.p[8], u, isb);  return; } u -= 20480;
    if (u < 20480) { Wc[OFF_SCV  + u] = ldi(a.p[9], u, isb);  return; } u -= 20480;
    if (u < 3200)  { Wc[OFF_WP   + u] = ldi(a.p[10], u, isb); return; } u -= 3200;
    if (u < 2048)  { Wc[OFF_LINS + u] = ldi(a.p[11], u, isb); return; } u -= 2048;
    Wc[OFF_LINV + u] = ldi(a.p[12], u, isb);
}

// ---- positions -> fp32 ----
__global__ __launch_bounds__(256) void posconv_kernel(const void* __restrict__ pos,
                                                      const int* __restrict__ flag,
                                                      float* __restrict__ posf) {
    int t = blockIdx.x * 256 + threadIdx.x;
    if (t >= N_ * 3) return;
    posf[t] = ldi(pos, t, *flag);
}

// ---- species from one-hot ----
__global__ __launch_bounds__(256) void spec_kernel(const void* __restrict__ attrs,
                                                   const int* __restrict__ flag,
                                                   int* __restrict__ spec) {
    int n = blockIdx.x * 256 + threadIdx.x;
    if (n >= N_) return;
    int isb = *flag;
    int z = 0;
    #pragma unroll
    for (int zz = 0; zz < Z_; zz++)
        if (ldi(attrs, n * Z_ + zz, isb) > 0.5f) z = zz;
    spec[n] = z;
}

// ---- s init: s[n][c] = W_embed[spec[n]][c] ----
__global__ __launch_bounds__(256) void sinit_kernel(const float* __restrict__ Wc,
                                                    const int* __restrict__ spec,
                                                    float* __restrict__ s) {
    int t = blockIdx.x * 256 + threadIdx.x;   // N*C threads
    int n = t >> 5, c = t & 31;
    s[t] = Wc[OFF_EMB + spec[n] * C_ + c];
}

// ---- dst-sort build step 1: per-dst degree of ACTIVE edges (r < RCUT) ----
__global__ __launch_bounds__(256) void deg_kernel(const int* __restrict__ ei,
                                                  const float* __restrict__ posf,
                                                  const void* __restrict__ shifts,
                                                  const int* __restrict__ flag,
                                                  int* __restrict__ rp) {
    int e = blockIdx.x * 256 + threadIdx.x;
    int isb = *flag;
    int s = ei[e], d = ei[E_ + e];
    if (s < 0 || s >= N_ || d < 0 || d >= N_) return;
    float vx = posf[d * 3 + 0] - posf[s * 3 + 0] + ldi(shifts, e * 3 + 0, isb);
    float vy = posf[d * 3 + 1] - posf[s * 3 + 1] + ldi(shifts, e * 3 + 1, isb);
    float vz = posf[d * 3 + 2] - posf[s * 3 + 2] + ldi(shifts, e * 3 + 2, isb);
    if (vx * vx + vy * vy + vz * vz < 25.0f) atomicAdd(rp + d, 1);
}

// ---- step 2: in-place exclusive prefix sum over rp[0..N); writes total to cnt ----
__global__ __launch_bounds__(1024) void scan_kernel(int* __restrict__ rp,
                                                    int* __restrict__ cnt) {
    __shared__ int ps[1024];
    int t = threadIdx.x;
    constexpr int CH = (N_ + 1023) / 1024;   // 49
    int base = t * CH;
    int sum = 0;
    for (int i = 0; i < CH; i++) {
        int idx = base + i;
        if (idx < N_) sum += rp[idx];
    }
    ps[t] = sum;
    __syncthreads();
    for (int off = 1; off < 1024; off <<= 1) {
        int v = (t >= off) ? ps[t - off] : 0;
        __syncthreads();
        ps[t] += v;
        __syncthreads();
    }
    int run = (t == 0) ? 0 : ps[t - 1];
    for (int i = 0; i < CH; i++) {
        int idx = base + i;
        if (idx < N_) { int v = rp[idx]; rp[idx] = run; run += v; }
    }
    if (t == 1023) cnt[0] = ps[1023];
}

// ---- step 3: counting-sort scatter of active edge ids by dst ----
__global__ __launch_bounds__(256) void scatter_kernel(const int* __restrict__ ei,
                                                      const float* __restrict__ posf,
                                                      const void* __restrict__ shifts,
                                                      const int* __restrict__ flag,
                                                      int* __restrict__ rp,
                                                      int* __restrict__ csr) {
    int e = blockIdx.x * 256 + threadIdx.x;
    int isb = *flag;
    int s = ei[e], d = ei[E_ + e];
    if (s < 0 || s >= N_ || d < 0 || d >= N_) return;
    float vx = posf[d * 3 + 0] - posf[s * 3 + 0] + ldi(shifts, e * 3 + 0, isb);
    float vy = posf[d * 3 + 1] - posf[s * 3 + 1] + ldi(shifts, e * 3 + 1, isb);
    float vz = posf[d * 3 + 2] - posf[s * 3 + 2] + ldi(shifts, e * 3 + 2, isb);
    if (vx * vx + vy * vy + vz * vz < 25.0f) {
        int pos = atomicAdd(rp + d, 1);
        csr[pos] = e;
    }
}

// ---- per-node "up" linear: su = s@Wus, vu = v@Wuv (fp32 math, bf16 outs) ----
__global__ __launch_bounds__(256) void up_kernel(const float* __restrict__ Wc,
                                                 const float* __restrict__ s,
                                                 const bf16* __restrict__ vb,
                                                 bf16* __restrict__ su,
                                                 bf16* __restrict__ vu, int layer) {
    __shared__ float s_sh[8][32];
    __shared__ float v_sh[8][96];
    int tid = threadIdx.x;
    int nl = tid >> 5, d = tid & 31;
    int n = blockIdx.x * 8 + nl;
    s_sh[nl][d]      = s[n * 32 + d];
    v_sh[nl][d]      = (float)vb[n * 96 + d];
    v_sh[nl][d + 32] = (float)vb[n * 96 + d + 32];
    v_sh[nl][d + 64] = (float)vb[n * 96 + d + 64];
    __syncthreads();
    const float* wus = Wc + OFF_UPS + layer * 1024;
    const float* wuv = Wc + OFF_UPV + layer * 1024;
    float a0 = 0.f, b0 = 0.f, b1 = 0.f, b2 = 0.f;
    #pragma unroll 8
    for (int c = 0; c < 32; c++) {
        float wS = wus[c * 32 + d], wV = wuv[c * 32 + d];
        a0 += s_sh[nl][c] * wS;
        b0 += v_sh[nl][c * 3 + 0] * wV;
        b1 += v_sh[nl][c * 3 + 1] * wV;
        b2 += v_sh[nl][c * 3 + 2] * wV;
    }
    su[n * 32 + d] = __float2bfloat16(a0);
    vu[n * 96 + d * 3 + 0] = __float2bfloat16(b0);
    vu[n * 96 + d * 3 + 1] = __float2bfloat16(b1);
    vu[n * 96 + d * 3 + 2] = __float2bfloat16(b2);
}

__device__ __forceinline__ float silu_f(float a) {
    return a / (1.f + __expf(-a));
}

// explicit 4-way select tree (no dynamic register indexing -> no scratch)
__device__ __forceinline__ float sel4(float a, float b, float c, float d, int l) {
    float ab = (l & 1) ? b : a;
    float cd = (l & 1) ? d : c;
    return (l & 2) ? cd : ab;
}

// segmented inclusive sum over the 16 groups of a wave (stride-4 lanes).
// hdv = index of this group's segment head (precomputed). After 4 steps,
// v[g] = sum of v over [hdv..g]; the run-last group then owns the run total.
__device__ __forceinline__ float segsum16(float v, int lane, int g, int hdv) {
    #pragma unroll
    for (int s = 1; s < 16; s <<= 1) {
        float u = __shfl(v, (lane - 4 * s) & 63, 64);
        if (g - s >= hdv) v += u;
    }
    return v;
}

// ---- fused edge kernel, 4 lanes per edge (round-0 proven codegen: all unrolls
// at kernel top level, 64 VGPR, zero scratch), now fed DST-SORTED edge slots ----
// Round-1/2 post-mortem: the per-node accumulator loop made clang keep h2/acc
// arrays in scratch (runtime-indexed inside an outer loop) -> GBs of HBM
// traffic. Reverted. Instead the atomic-throughput bottleneck (29M scattered
// L2 atomics, 444 MB writebacks) is cut by a wave-level SEGMENTED REDUCTION:
// eids is sorted by dst, so the 16 consecutive slots in a wave form few
// same-dst runs; values are pre-summed across each run (4-step stride-4
// Hillis-Steele) and only the run-last group issues atomics (~4x fewer, and
// targeting contiguous lines).
__global__ __launch_bounds__(256, 4) void msg_kernel(const int* __restrict__ eids,
                                                     const int* __restrict__ cnt,
                                                     const int* __restrict__ ei,
                                                     const float* __restrict__ posf,
                                                     const void* __restrict__ shifts,
                                                     const int* __restrict__ flag,
                                                     const float* __restrict__ Wc,
                                                     const bf16* __restrict__ sub,
                                                     const bf16* __restrict__ vub,
                                                     float* __restrict__ S,
                                                     float* __restrict__ V, int layer) {
    int tid = threadIdx.x;
    int lane = tid & 63;
    int waveid = tid >> 6;
    int g = lane >> 2;                 // group within wave (0..15)
    int l = lane & 3;                  // lane within group (0..3)
    int total = cnt[0];
    int base = blockIdx.x * 64 + waveid * 16;
    if (base >= total) return;         // wave-uniform early out
    int i0 = base + g;
    bool valid = (i0 < total);
    int i = valid ? i0 : (total - 1);  // clamp tail; contribution zeroed via scale
    int isb = *flag;
    int e = eids[i];
    int srcn = ei[e], dstn = ei[E_ + e];
    float scale = valid ? 0.0625f : 0.0f;

    // ---- segment topology across the 16 groups (dst-sorted slots) ----
    int dstp = __shfl(dstn, (lane - 4) & 63, 64);
    int dstx = __shfl(dstn, (lane + 4) & 63, 64);
    bool head = (g == 0) || (dstp != dstn);
    bool last = (g == 15) || (dstx != dstn);
    int hdv = head ? g : 0;            // unsegmented max-scan -> most recent head
    #pragma unroll
    for (int s = 1; s < 16; s <<= 1) {
        int o = __shfl(hdv, (lane - 4 * s) & 63, 64);
        if (g >= s) hdv = max(hdv, o);
    }

    // ---- EARLY raw gathers (strided channels c = 4t + l), latency hidden by MLP ----
    const unsigned short* sp = (const unsigned short*)(sub + (size_t)srcn * 32 + l);
    const unsigned short* vp = (const unsigned short*)(vub + (size_t)srcn * 96 + 3 * l);
    unsigned short sraw[8];
    unsigned short vraw[8][3];
    #pragma unroll
    for (int t = 0; t < 8; t++) {
        sraw[t]    = sp[4 * t];
        vraw[t][0] = vp[12 * t + 0];
        vraw[t][1] = vp[12 * t + 1];
        vraw[t][2] = vp[12 * t + 2];
    }

    float vx = posf[dstn * 3 + 0] - posf[srcn * 3 + 0] + ldi(shifts, e * 3 + 0, isb);
    float vy = posf[dstn * 3 + 1] - posf[srcn * 3 + 1] + ldi(shifts, e * 3 + 1, isb);
    float vz = posf[dstn * 3 + 2] - posf[srcn * 3 + 2] + ldi(shifts, e * 3 + 2, isb);
    float r2 = vx * vx + vy * vy + vz * vz;
    float r = sqrtf(r2);
    float rs = fmaxf(r, 1e-9f);
    float inv = 1.0f / rs;
    float Yx = vx * inv, Yy = vy * inv, Yz = vz * inv;

    // edge_feats = sqrt(2/5)*sin(n*pi*rs/5)/rs * fc(r/5)
    float x = r * 0.2f;
    float x2 = x * x, x3 = x2 * x, x6 = x3 * x3, x7 = x6 * x, x8 = x7 * x;
    float fcv = 1.f - 28.f * x6 + 48.f * x7 - 21.f * x8;
    float scl = 0.63245553203367587f * inv * fcv;
    float ang = 0.62831853071795865f * rs;   // pi/5 * rs
    float ef[8];
    #pragma unroll
    for (int q = 0; q < 8; q++) ef[q] = scl * sinf(ang * (float)(q + 1));

    // radial MLP: each lane owns h2[jbase .. jbase+16)
    const int jbase = l * 16;
    const float* r1 = Wc + OFF_R1T + layer * 512;   // [64][8]
    const float* r2w = Wc + OFF_R2 + layer * 4096;  // [64][64]
    float h2[16];
    #pragma unroll
    for (int jj = 0; jj < 16; jj++) h2[jj] = 0.f;
    for (int k = 0; k < 64; k++) {
        float a = 0.f;
        #pragma unroll
        for (int q = 0; q < 8; q++) a += ef[q] * r1[k * 8 + q];
        float h1k = silu_f(a);
        const float4* row = (const float4*)(r2w + k * 64 + jbase);
        #pragma unroll
        for (int jj4 = 0; jj4 < 4; jj4++) {
            float4 rv = row[jj4];
            h2[jj4 * 4 + 0] += h1k * rv.x;
            h2[jj4 * 4 + 1] += h1k * rv.y;
            h2[jj4 * 4 + 2] += h1k * rv.z;
            h2[jj4 * 4 + 3] += h1k * rv.w;
        }
    }
    #pragma unroll
    for (int jj = 0; jj < 16; jj++) h2[jj] = silu_f(h2[jj]);

    const float* r3l = Wc + OFF_R3T + layer * 10240;  // [32][5][64] c-major
    float* Sd = S + (size_t)dstn * 32;
    float* Vd = V + (size_t)dstn * 96;

    #pragma unroll
    for (int c4 = 0; c4 < 8; c4++) {
        const int c0 = c4 * 4;
        float wp[5][4];
        #pragma unroll
        for (int p = 0; p < 5; p++) {
            #pragma unroll
            for (int cc2 = 0; cc2 < 4; cc2++) {
                const float4* rp4 = (const float4*)(r3l + (c0 + cc2) * 320 + p * 64 + jbase);
                float acc = 0.f;
                #pragma unroll
                for (int jj4 = 0; jj4 < 4; jj4++) {
                    float4 rv = rp4[jj4];
                    acc += h2[jj4 * 4 + 0] * rv.x + h2[jj4 * 4 + 1] * rv.y
                         + h2[jj4 * 4 + 2] * rv.z + h2[jj4 * 4 + 3] * rv.w;
                }
                wp[p][cc2] = acc;
            }
        }
        // butterfly reduce across the 4-lane group (xor 1, 2 stay in group)
        #pragma unroll
        for (int p = 0; p < 5; p++) {
            #pragma unroll
            for (int cc2 = 0; cc2 < 4; cc2++) {
                float v = wp[p][cc2];
                v += __shfl_xor(v, 1, 64);
                v += __shfl_xor(v, 2, 64);
                wp[p][cc2] = v;
            }
        }
        // lane l owns channel c0 + l
        const int c = c0 + l;
        float w0 = sel4(wp[0][0], wp[0][1], wp[0][2], wp[0][3], l);
        float w1 = sel4(wp[1][0], wp[1][1], wp[1][2], wp[1][3], l);
        float w2 = sel4(wp[2][0], wp[2][1], wp[2][2], wp[2][3], l);
        float w3 = sel4(wp[3][0], wp[3][1], wp[3][2], wp[3][3], l);
        float w4 = sel4(wp[4][0], wp[4][1], wp[4][2], wp[4][3], l);

        float ss  = b2f(sraw[c4]);
        float vvx = b2f(vraw[c4][0]);
        float vvy = b2f(vraw[c4][1]);
        float vvz = b2f(vraw[c4][2]);
        float dt = vvx * Yx + vvy * Yy + vvz * Yz;
        float cx = vvy * Yz - vvz * Yy;
        float cy = vvz * Yx - vvx * Yz;
        float cz = vvx * Yy - vvy * Yx;
        float ms = (w0 * ss + w3 * dt) * scale;
        float mx = (w1 * ss * Yx + w2 * vvx + w4 * cx) * scale;
        float my = (w1 * ss * Yy + w2 * vvy + w4 * cy) * scale;
        float mz = (w1 * ss * Yz + w2 * vvz + w4 * cz) * scale;

        // pre-sum each same-dst run; only the run-last group issues atomics
        ms = segsum16(ms, lane, g, hdv);
        mx = segsum16(mx, lane, g, hdv);
        my = segsum16(my, lane, g, hdv);
        mz = segsum16(mz, lane, g, hdv);
        if (last) {
            atomicAdd(Sd + c, ms);
            atomicAdd(Vd + c * 3 + 0, mx);
            atomicAdd(Vd + c * 3 + 1, my);
            atomicAdd(Vd + c * 3 + 2, mz);
        }
    }
}

// ---- per-node post: out/skip/product/linear, writes invariants + new s,v in-place ----
__global__ __launch_bounds__(256) void post_kernel(const float* __restrict__ Wc,
                                                   const float* __restrict__ Sb,
                                                   const float* __restrict__ Vb,
                                                   float* __restrict__ s,
                                                   bf16* __restrict__ vbst,
                                                   const int* __restrict__ spec,
                                                   float* __restrict__ out, int layer) {
    __shared__ float A_s[8][32];
    __shared__ float A_v[8][96];
    __shared__ float B_s[8][32];
    __shared__ float B_v[8][96];
    int tid = threadIdx.x;
    int nl = tid >> 5, d = tid & 31;
    int n = blockIdx.x * 8 + nl;
    A_s[nl][d]      = Sb[n * 32 + d];
    A_v[nl][d]      = Vb[n * 96 + d];
    A_v[nl][d + 32] = Vb[n * 96 + d + 32];
    A_v[nl][d + 64] = Vb[n * 96 + d + 64];
    B_s[nl][d]      = s[n * 32 + d];
    B_v[nl][d]      = (float)vbst[n * 96 + d];
    B_v[nl][d + 32] = (float)vbst[n * 96 + d + 32];
    B_v[nl][d + 64] = (float)vbst[n * 96 + d + 64];
    __syncthreads();

    int z = spec[n];
    const float* wos = Wc + OFF_OUTS + layer * 1024;
    const float* wov = Wc + OFF_OUTV + layer * 1024;
    const float* wss = Wc + OFF_SCS + (layer * Z_ + z) * 1024;
    const float* wsv = Wc + OFF_SCV + (layer * Z_ + z) * 1024;
    float s2 = 0.f, v20 = 0.f, v21 = 0.f, v22 = 0.f;
    float scs = 0.f, scv0 = 0.f, scv1 = 0.f, scv2 = 0.f;
    #pragma unroll 8
    for (int c = 0; c < 32; c++) {
        float wo = wos[c * 32 + d], wv = wov[c * 32 + d];
        float wa = wss[c * 32 + d], wb = wsv[c * 32 + d];
        s2  += A_s[nl][c] * wo;
        v20 += A_v[nl][c * 3 + 0] * wv;
        v21 += A_v[nl][c * 3 + 1] * wv;
        v22 += A_v[nl][c * 3 + 2] * wv;
        scs  += B_s[nl][c] * wa;
        scv0 += B_v[nl][c * 3 + 0] * wb;
        scv1 += B_v[nl][c * 3 + 1] * wb;
        scv2 += B_v[nl][c * 3 + 2] * wb;
    }
    const float* wp = Wc + OFF_WP + (layer * Z_ + z) * 160;
    float we0 = wp[d], we1 = wp[32 + d], we2 = wp[64 + d], we3 = wp[96 + d], we4 = wp[128 + d];
    float ps = we0 * s2 + we1 * s2 * s2 + we2 * (v20 * v20 + v21 * v21 + v22 * v22);
    float pv0 = we3 * v20 + we4 * s2 * v20;
    float pv1 = we3 * v21 + we4 * s2 * v21;
    float pv2 = we3 * v22 + we4 * s2 * v22;
    __syncthreads();
    A_s[nl][d] = ps;
    A_v[nl][d * 3 + 0] = pv0;
    A_v[nl][d * 3 + 1] = pv1;
    A_v[nl][d * 3 + 2] = pv2;
    __syncthreads();
    const float* wls = Wc + OFF_LINS + layer * 1024;
    const float* wlv = Wc + OFF_LINV + layer * 1024;
    float sn = scs, vn0 = scv0, vn1 = scv1, vn2 = scv2;
    #pragma unroll 8
    for (int c = 0; c < 32; c++) {
        float wl = wls[c * 32 + d], w2_ = wlv[c * 32 + d];
        sn  += A_s[nl][c] * wl;
        vn0 += A_v[nl][c * 3 + 0] * w2_;
        vn1 += A_v[nl][c * 3 + 1] * w2_;
        vn2 += A_v[nl][c * 3 + 2] * w2_;
    }
    s[n * 32 + d] = sn;
    out[(size_t)n * 64 + layer * 32 + d] = sn;   // fp32 output (verified round 5)
    vbst[n * 96 + d * 3 + 0] = __float2bfloat16(vn0);
    vbst[n * 96 + d * 3 + 1] = __float2bfloat16(vn1);
    vbst[n * 96 + d * 3 + 2] = __float2bfloat16(vn2);
}

// Host-side: resolve input pointers by element count (robust to harness input
// ordering). Greedy first-unused match preserves relative order within equal
// sizes, so if the harness order == reference dict order this is the identity.
static void resolve_inputs(const int* in_sizes, int n_in, int idx[17]) {
    const int want[17] = {150000, 500000, 2400000, 320, 2048, 2048, 1024, 8192,
                          20480, 2048, 2048, 20480, 20480, 3200, 2048, 2048, 1600000};
    for (int k = 0; k < 17; k++) idx[k] = k;   // default identity
    if (!in_sizes || n_in < 17) return;
    bool used[64];
    for (int i = 0; i < 64; i++) used[i] = false;
    int tmp[17];
    for (int k = 0; k < 17; k++) {
        int found = -1;
        for (int i = 0; i < n_in && i < 64; i++) {
            if (!used[i] && in_sizes[i] == want[k]) { found = i; break; }
        }
        if (found < 0) return;               // sizes don't match expectation: keep identity
        used[found] = true;
        tmp[k] = found;
    }
    for (int k = 0; k < 17; k++) idx[k] = tmp[k];
}

extern "C" void kernel_launch(void* const* d_in, const int* in_sizes, int n_in,
                              void* d_out, int out_size, void* d_ws, size_t ws_size,
                              hipStream_t stream) {
    (void)out_size; (void)ws_size;
    int idx[17];
    resolve_inputs(in_sizes, n_in, idx);

    const void* pos    = d_in[idx[0]];
    const void* attrs  = d_in[idx[1]];
    const void* shifts = d_in[idx[2]];
    const int*  ei     = (const int*)d_in[idx[16]];
    float* out = (float*)d_out;

    int*   I = (int*)d_ws;
    float* W = (float*)d_ws;

    hipMemsetAsync(I, 0, 64 * sizeof(int), stream);                             // cnt + flag
    hipMemsetAsync(I + O_ROWP, 0, 50048 * sizeof(int), stream);                 // degrees
    hipMemsetAsync(W + O_VB, 0, (size_t)N_ * C_ * 3 * sizeof(bf16), stream);    // v state = 0

    detect_kernel<<<1, 256, 0, stream>>>((const unsigned*)attrs, I + O_FLAG);

    ConvArgs ca;
    for (int k = 0; k < 13; k++) ca.p[k] = d_in[idx[3 + k]];
    convert_kernel<<<(W_TOTAL + 255) / 256, 256, 0, stream>>>(ca, I + O_FLAG, W + O_W);
    posconv_kernel<<<(N_ * 3 + 255) / 256, 256, 0, stream>>>(pos, I + O_FLAG, W + O_POSF);
    spec_kernel<<<(N_ + 255) / 256, 256, 0, stream>>>(attrs, I + O_FLAG, I + O_SPEC);
    sinit_kernel<<<(N_ * C_) / 256, 256, 0, stream>>>(W + O_W, I + O_SPEC, W + O_S);

    // one-time dst-sorted active-edge list (counting sort; graph static across layers)
    deg_kernel<<<E_ / 256, 256, 0, stream>>>(ei, W + O_POSF, shifts, I + O_FLAG, I + O_ROWP);
    scan_kernel<<<1, 1024, 0, stream>>>(I + O_ROWP, I + O_CNT);
    scatter_kernel<<<E_ / 256, 256, 0, stream>>>(ei, W + O_POSF, shifts, I + O_FLAG,
                                                 I + O_ROWP, I + O_EIDS);

    for (int l = 0; l < 2; l++) {
        up_kernel<<<N_ / 8, 256, 0, stream>>>(W + O_W, W + O_S, (const bf16*)(W + O_VB),
                                              (bf16*)(W + O_SUB), (bf16*)(W + O_VUB), l);
        hipMemsetAsync(W + O_SS, 0, (size_t)N_ * C_ * 4 * sizeof(float), stream);  // SS+VV
        msg_kernel<<<(E_ + 63) / 64, 256, 0, stream>>>(I + O_EIDS, I + O_CNT, ei,
                                                       W + O_POSF, shifts, I + O_FLAG, W + O_W,
                                                       (const bf16*)(W + O_SUB),
                                                       (const bf16*)(W + O_VUB),
                                                       W + O_SS, W + O_VV, l);
        post_kernel<<<N_ / 8, 256, 0, stream>>>(W + O_W, W + O_SS, W + O_VV,
                                                W + O_S, (bf16*)(W + O_VB),
                                                I + O_SPEC, out, l);
    }
}